// Round 3
// baseline (4932.042 us; speedup 1.0000x reference)
//
#include <hip/hip_runtime.h>

#define N_ROWS 32768
#define DIM 256
#define N_CODES 8192
#define OUT_Q 8388608        // N_ROWS*DIM
#define OUT_LOSS 8388608
#define OUT_IDX 8388609
#define FLAG_GAP 1e-4f       // ~3 score-grid cells (grid = ulp(~256) ≈ 3.05e-5)

// ws layout (bytes)
#define WS_AROW 0            // 32768 f32
#define WS_IDX  131072       // 32768 i32
#define WS_LIST 262144       // 32768 i32
#define WS_CNT  393216       // 1 i32 (+pad)
#define WS_PART 393472       // 32768 f32

__device__ __forceinline__ unsigned long long umin64(unsigned long long a, unsigned long long b) {
    return a < b ? a : b;
}
__device__ __forceinline__ unsigned long long umax64(unsigned long long a, unsigned long long b) {
    return a > b ? a : b;
}
// order-preserving float->uint map: f<g  <=>  fkey(f)<fkey(g)
__device__ __forceinline__ unsigned int fkey(float f) {
    unsigned int b = __float_as_uint(f);
    return b ^ (unsigned int)(((int)b >> 31) | 0x80000000);
}
__device__ __forceinline__ float fkeyinv(unsigned int u) {
    unsigned int b = (u >> 31) ? (u ^ 0x80000000u) : ~u;
    return __uint_as_float(b);
}

// ---------------- Kernel A: per-row ||x||^2 in fp64 -> fp32 ----------------
__global__ void vq_rowA(const float* __restrict__ X, float* __restrict__ Arow) {
    int row = blockIdx.x * 4 + (threadIdx.x >> 6);
    int lane = threadIdx.x & 63;
    const float4 v = *((const float4*)(X + (size_t)row * DIM + lane * 4));
    double s = (double)v.x * v.x + (double)v.y * v.y + (double)v.z * v.z + (double)v.w * v.w;
#pragma unroll
    for (int m = 1; m < 64; m <<= 1) s += __shfl_xor(s, m, 64);
    if (lane == 0) Arow[row] = (float)s;
}

// ------- Kernel B: fused GEMM + np-semantics score argmin (top-2, flags) -------
__global__ __launch_bounds__(256, 2) void vq_argmin(
    const float* __restrict__ X, const float* __restrict__ E,
    const float* __restrict__ Arow, int* __restrict__ ws_idx,
    int* __restrict__ flaglist, int* __restrict__ flagcnt) {
    __shared__ float xs[DIM][64];   // [dim][row]  transposed, 64 KB
    __shared__ float es[64][64];    // [dim_local][code] transposed, 16 KB

    const int tid = threadIdx.x;
    const int r0 = blockIdx.x * 64;

    // stage X transposed: xs[k][row] = X[r0+row][k]
    {
        const int row = tid >> 2, q = tid & 3;
        const float* gX = X + (size_t)(r0 + row) * DIM;
#pragma unroll
        for (int w = 0; w < 16; ++w) {
            float4 v = *((const float4*)(gX + w * 16 + q * 4));
            int k = w * 16 + q * 4;
            xs[k + 0][row] = v.x;
            xs[k + 1][row] = v.y;
            xs[k + 2][row] = v.z;
            xs[k + 3][row] = v.w;
        }
    }

    const int tc = tid & 15;   // codes 4*tc..4*tc+3 within tile
    const int tr = tid >> 4;   // rows  4*tr..4*tr+3

    float A[4];
#pragma unroll
    for (int i = 0; i < 4; ++i) A[i] = Arow[r0 + 4 * tr + i];

    unsigned long long K1[4], K2[4];
#pragma unroll
    for (int i = 0; i < 4; ++i) { K1[i] = ~0ull; K2[i] = ~0ull; }

    __syncthreads();

    for (int tile = 0; tile < 128; ++tile) {
        const int c0 = tile * 64;
        float acc[4][4] = {};  // [row i][code j]

        for (int chunk = 0; chunk < 4; ++chunk) {
            __syncthreads();
            // stage E transposed: es[kl][c] = E[c0+c][chunk*64+kl]
            {
                const int c = tid >> 2, q = tid & 3;
                const float* gE = E + (size_t)(c0 + c) * DIM + chunk * 64;
#pragma unroll
                for (int w = 0; w < 4; ++w) {
                    float4 v = *((const float4*)(gE + w * 16 + q * 4));
                    int kl = w * 16 + q * 4;
                    es[kl + 0][c] = v.x;
                    es[kl + 1][c] = v.y;
                    es[kl + 2][c] = v.z;
                    es[kl + 3][c] = v.w;
                }
            }
            __syncthreads();
#pragma unroll 8
            for (int kl = 0; kl < 64; ++kl) {
                const float4 xv = *((const float4*)&xs[chunk * 64 + kl][4 * tr]);
                const float4 ev = *((const float4*)&es[kl][4 * tc]);
                acc[0][0] = fmaf(xv.x, ev.x, acc[0][0]);
                acc[0][1] = fmaf(xv.x, ev.y, acc[0][1]);
                acc[0][2] = fmaf(xv.x, ev.z, acc[0][2]);
                acc[0][3] = fmaf(xv.x, ev.w, acc[0][3]);
                acc[1][0] = fmaf(xv.y, ev.x, acc[1][0]);
                acc[1][1] = fmaf(xv.y, ev.y, acc[1][1]);
                acc[1][2] = fmaf(xv.y, ev.z, acc[1][2]);
                acc[1][3] = fmaf(xv.y, ev.w, acc[1][3]);
                acc[2][0] = fmaf(xv.z, ev.x, acc[2][0]);
                acc[2][1] = fmaf(xv.z, ev.y, acc[2][1]);
                acc[2][2] = fmaf(xv.z, ev.z, acc[2][2]);
                acc[2][3] = fmaf(xv.z, ev.w, acc[2][3]);
                acc[3][0] = fmaf(xv.w, ev.x, acc[3][0]);
                acc[3][1] = fmaf(xv.w, ev.y, acc[3][1]);
                acc[3][2] = fmaf(xv.w, ev.z, acc[3][2]);
                acc[3][3] = fmaf(xv.w, ev.w, acc[3][3]);
            }
        }

        // per-row top-2 of np-score fl32(A - 2*M), butterfly over 16 tc-lanes
#pragma unroll
        for (int i = 0; i < 4; ++i) {
            unsigned long long k1 = ~0ull, k2 = ~0ull;
#pragma unroll
            for (int j = 0; j < 4; ++j) {
                float v = A[i] - 2.0f * acc[i][j];   // fp32: reproduces np rounding grid
                unsigned long long key =
                    ((unsigned long long)fkey(v) << 32) | (unsigned int)(c0 + 4 * tc + j);
                unsigned long long mx = umax64(k1, key);
                k1 = umin64(k1, key);
                k2 = umin64(k2, mx);
            }
#pragma unroll
            for (int m = 1; m < 16; m <<= 1) {
                unsigned long long o1 = __shfl_xor(k1, m, 64);
                unsigned long long o2 = __shfl_xor(k2, m, 64);
                unsigned long long mx = umax64(k1, o1);
                k1 = umin64(k1, o1);
                k2 = umin64(umin64(k2, o2), mx);
            }
            unsigned long long mx = umax64(K1[i], k1);
            K1[i] = umin64(K1[i], k1);
            K2[i] = umin64(umin64(K2[i], k2), mx);
        }
    }

    if (tc == 0) {
#pragma unroll
        for (int i = 0; i < 4; ++i) {
            int r = r0 + 4 * tr + i;
            ws_idx[r] = (int)(unsigned int)(K1[i] & 0xFFFFFFFFull);
            float s1 = fkeyinv((unsigned int)(K1[i] >> 32));
            float s2 = fkeyinv((unsigned int)(K2[i] >> 32));
            if (s2 - s1 < FLAG_GAP) {
                int slot = atomicAdd(flagcnt, 1);
                flaglist[slot] = r;
            }
        }
    }
}

// ------- Kernel C: np-semantics refine of flagged rows (fp64 dot -> fp32 score) -------
__global__ __launch_bounds__(256) void vq_refine_np(
    const float* __restrict__ X, const float* __restrict__ E,
    const float* __restrict__ Arow, int* __restrict__ ws_idx,
    const int* __restrict__ flaglist, const int* __restrict__ flagcnt) {
    __shared__ float xs[DIM][64];
    __shared__ float es[64][64];

    const int tid = threadIdx.x;
    const int tc = tid & 15, tr = tid >> 4;
    const int cnt = *flagcnt;

    for (int g = blockIdx.x; g * 64 < cnt; g += gridDim.x) {
        __syncthreads();   // protect xs from previous iteration's readers
        // stage flagged rows' X, transposed (row list via flaglist, clamped padding)
        int myrow[1];
        {
            const int row = tid >> 2, q = tid & 3;
            int s = g * 64 + row;
            int r = flaglist[s < cnt ? s : cnt - 1];
            myrow[0] = r;
            const float* gX = X + (size_t)r * DIM;
#pragma unroll
            for (int w = 0; w < 16; ++w) {
                float4 v = *((const float4*)(gX + w * 16 + q * 4));
                int k = w * 16 + q * 4;
                xs[k + 0][row] = v.x;
                xs[k + 1][row] = v.y;
                xs[k + 2][row] = v.z;
                xs[k + 3][row] = v.w;
            }
        }
        (void)myrow;
        int rowid[4];
        float Ar[4];
#pragma unroll
        for (int i = 0; i < 4; ++i) {
            int s = g * 64 + 4 * tr + i;
            rowid[i] = flaglist[s < cnt ? s : cnt - 1];
            Ar[i] = Arow[rowid[i]];
        }
        unsigned long long K1[4];
#pragma unroll
        for (int i = 0; i < 4; ++i) K1[i] = ~0ull;

        for (int tile = 0; tile < 128; ++tile) {
            const int c0 = tile * 64;
            double acc[4][4] = {};
            for (int chunk = 0; chunk < 4; ++chunk) {
                __syncthreads();
                {
                    const int c = tid >> 2, q = tid & 3;
                    const float* gE = E + (size_t)(c0 + c) * DIM + chunk * 64;
#pragma unroll
                    for (int w = 0; w < 4; ++w) {
                        float4 v = *((const float4*)(gE + w * 16 + q * 4));
                        int kl = w * 16 + q * 4;
                        es[kl + 0][c] = v.x;
                        es[kl + 1][c] = v.y;
                        es[kl + 2][c] = v.z;
                        es[kl + 3][c] = v.w;
                    }
                }
                __syncthreads();
#pragma unroll 2
                for (int kl = 0; kl < 64; ++kl) {
                    const float4 xv = *((const float4*)&xs[chunk * 64 + kl][4 * tr]);
                    const float4 ev = *((const float4*)&es[kl][4 * tc]);
                    const double xd[4] = {(double)xv.x, (double)xv.y, (double)xv.z, (double)xv.w};
                    const double ed[4] = {(double)ev.x, (double)ev.y, (double)ev.z, (double)ev.w};
#pragma unroll
                    for (int i = 0; i < 4; ++i)
#pragma unroll
                        for (int j = 0; j < 4; ++j) acc[i][j] = fma(xd[i], ed[j], acc[i][j]);
                }
            }
#pragma unroll
            for (int i = 0; i < 4; ++i) {
#pragma unroll
                for (int j = 0; j < 4; ++j) {
                    float m32 = (float)acc[i][j];          // correctly-rounded fp32 dot
                    float scr = Ar[i] - 2.0f * m32;        // np-semantics fp32 score
                    unsigned long long key =
                        ((unsigned long long)fkey(scr) << 32) | (unsigned int)(c0 + 4 * tc + j);
                    K1[i] = umin64(K1[i], key);
                }
            }
        }
#pragma unroll
        for (int i = 0; i < 4; ++i) {
#pragma unroll
            for (int m = 1; m < 16; m <<= 1) K1[i] = umin64(K1[i], __shfl_xor(K1[i], m, 64));
        }
        if (tc == 0) {
#pragma unroll
            for (int i = 0; i < 4; ++i) {
                int s = g * 64 + 4 * tr + i;
                if (s < cnt) ws_idx[rowid[i]] = (int)(unsigned int)(K1[i] & 0xFFFFFFFFull);
            }
        }
    }
}

// ---------------- Kernel D: gather quantized (ST-mimic), loss partials ----------------
__global__ void vq_out(const float* __restrict__ X, const float* __restrict__ E,
                       const int* __restrict__ ws_idx, float* __restrict__ out,
                       float* __restrict__ partials) {
    const int r = (blockIdx.x * 256 + threadIdx.x) >> 6;   // one wave per row
    const int lane = threadIdx.x & 63;
    const int idx = ws_idx[r];
    float4 e = *((const float4*)(E + (size_t)idx * DIM + lane * 4));
    float4 x = *((const float4*)(X + (size_t)r * DIM + lane * 4));
    float dx = e.x - x.x, dy = e.y - x.y, dz = e.z - x.z, dw = e.w - x.w;
    float4 o;
    o.x = x.x + dx; o.y = x.y + dy; o.z = x.z + dz; o.w = x.w + dw;
    *((float4*)(out + (size_t)r * DIM + lane * 4)) = o;
    float s = dx * dx + dy * dy + dz * dz + dw * dw;
#pragma unroll
    for (int m = 1; m < 64; m <<= 1) s += __shfl_xor(s, m, 64);
    if (lane == 0) {
        partials[r] = s;
        out[OUT_IDX + r] = (float)idx;
    }
}

// ---------------- Kernel E: deterministic loss reduction ----------------
__global__ void vq_loss(const float* __restrict__ partials, float* __restrict__ out) {
    __shared__ double sred[4];
    double s = 0.0;
    for (int i = threadIdx.x; i < N_ROWS; i += 256) s += (double)partials[i];
#pragma unroll
    for (int m = 1; m < 64; m <<= 1) s += __shfl_xor(s, m, 64);
    if ((threadIdx.x & 63) == 0) sred[threadIdx.x >> 6] = s;
    __syncthreads();
    if (threadIdx.x == 0) {
        double t = sred[0] + sred[1] + sred[2] + sred[3];
        out[OUT_LOSS] = (float)(2.0 * t / (double)OUT_Q);
    }
}

extern "C" void kernel_launch(void* const* d_in, const int* in_sizes, int n_in,
                              void* d_out, int out_size, void* d_ws, size_t ws_size,
                              hipStream_t stream) {
    const float* X = (const float*)d_in[0];
    const float* E = (const float*)d_in[1];
    float* out = (float*)d_out;
    char* ws = (char*)d_ws;

    float* Arow = (float*)(ws + WS_AROW);
    int* idx = (int*)(ws + WS_IDX);
    int* list = (int*)(ws + WS_LIST);
    int* cnt = (int*)(ws + WS_CNT);
    float* part = (float*)(ws + WS_PART);

    hipMemsetAsync(cnt, 0, sizeof(int), stream);
    vq_rowA<<<N_ROWS / 4, 256, 0, stream>>>(X, Arow);
    vq_argmin<<<N_ROWS / 64, 256, 0, stream>>>(X, E, Arow, idx, list, cnt);
    vq_refine_np<<<512, 256, 0, stream>>>(X, E, Arow, idx, list, cnt);
    vq_out<<<N_ROWS / 4, 256, 0, stream>>>(X, E, idx, out, part);
    vq_loss<<<1, 256, 0, stream>>>(part, out);
}

// Round 4
// 1368.860 us; speedup vs baseline: 3.6030x; 3.6030x over previous
//
#include <hip/hip_runtime.h>

#define N_ROWS 32768
#define DIM 256
#define N_CODES 8192
#define OUT_Q 8388608        // N_ROWS*DIM
#define OUT_LOSS 8388608
#define OUT_IDX 8388609
#define FLAG_GAP 7e-5f       // >= 2 grid cells at g=3.05e-5 (A in [256,512)) -> provably safe

// ws small layout (bytes)
#define WS_AROW 0            // 32768 f32
#define WS_IDX  131072       // 32768 i32
#define WS_LIST 262144       // 32768 i32
#define WS_CNT  393216       // 1 i32 (+pad)
#define WS_KEYS 393472       // 32768 u64 (256KB)
#define WS_PART 655616       // 32768 f32
#define WS_EIMG 1048576      // 8MB E-image if ws_size allows, else use d_out as scratch

typedef __attribute__((ext_vector_type(8))) short short8x;
typedef __attribute__((ext_vector_type(4))) float f32x4;
typedef unsigned long long u64;
#define AS1 __attribute__((address_space(1)))
#define AS3 __attribute__((address_space(3)))

__device__ __forceinline__ u64 umin64(u64 a, u64 b) { return a < b ? a : b; }
__device__ __forceinline__ u64 umax64(u64 a, u64 b) { return a > b ? a : b; }
// order-preserving float->uint map
__device__ __forceinline__ unsigned fkey(float f) {
    unsigned b = __float_as_uint(f);
    return b ^ (unsigned)(((int)b >> 31) | 0x80000000);
}
__device__ __forceinline__ float fkeyinv(unsigned u) {
    unsigned b = (u >> 31) ? (u ^ 0x80000000u) : ~u;
    return __uint_as_float(b);
}
__device__ __forceinline__ unsigned short bf16rne(float f) {
    unsigned u = __float_as_uint(f);
    return (unsigned short)((u + 0x7fff + ((u >> 16) & 1)) >> 16);
}
__device__ __forceinline__ void gload16(const void* g, void* l) {
    __builtin_amdgcn_global_load_lds((const AS1 unsigned int*)g, (AS3 unsigned int*)l, 16, 0, 0);
}

// ---------------- Kernel P: E -> bf16 h/l split, frag-linear chunk images ----------------
// Image: 256 chunk-blocks (tile 0..31 x kstep 0..7) of 32KB:
//   offset(cb, plane, sub, code) = cb*32768 + plane*16384 + sub*4096 + code*16
//   contents: 8 bf16 of plane(E[tile*256+code][S*32+sub*8 + 0..7])
__global__ void vq_prepE(const float* __restrict__ E, char* __restrict__ Eimg) {
    int t = blockIdx.x * 256 + threadIdx.x;   // 0..262143
    int cb = t >> 10;
    int u = t & 1023;
    int sub = u >> 8, code = u & 255;
    int tile = cb >> 3, S = cb & 7;
    const float* src = E + (size_t)(tile * 256 + code) * DIM + S * 32 + sub * 8;
    unsigned short h[8], l[8];
#pragma unroll
    for (int j = 0; j < 8; ++j) {
        float v = src[j];
        h[j] = bf16rne(v);
        float hf = __uint_as_float((unsigned)h[j] << 16);
        l[j] = bf16rne(v - hf);
    }
    short8x H, L;
#pragma unroll
    for (int j = 0; j < 8; ++j) { H[j] = (short)h[j]; L[j] = (short)l[j]; }
    char* dst = Eimg + (size_t)cb * 32768 + sub * 4096 + code * 16;
    *(short8x*)dst = H;
    *(short8x*)(dst + 16384) = L;
}

// ---------------- Kernel A: per-row ||x||^2 in fp64 -> fp32 ----------------
__global__ void vq_rowA(const float* __restrict__ X, float* __restrict__ Arow) {
    int row = blockIdx.x * 4 + (threadIdx.x >> 6);
    int lane = threadIdx.x & 63;
    const float4 v = *((const float4*)(X + (size_t)row * DIM + lane * 4));
    double s = (double)v.x * v.x + (double)v.y * v.y + (double)v.z * v.z + (double)v.w * v.w;
#pragma unroll
    for (int m = 1; m < 64; m <<= 1) s += __shfl_xor(s, m, 64);
    if (lane == 0) Arow[row] = (float)s;
}

// ------- Kernel B: MFMA split-bf16 distance GEMM + np-score top-2 argmin -------
__global__ __launch_bounds__(256, 1) void vq_argmin(
    const float* __restrict__ X, const char* __restrict__ Eimg,
    const float* __restrict__ Arow, int* __restrict__ ws_idx,
    int* __restrict__ flaglist, int* __restrict__ flagcnt, u64* __restrict__ keybuf) {
    __shared__ unsigned short Xs[32768];     // 64KB: h plane [0,32KB), l plane [32KB,64KB)
    __shared__ unsigned short Eb[2][16384];  // 2 x 32KB double-buffered E chunk
    __shared__ u64 red[4][64][2];            // cross-wave top-2 merge

    const int tid = threadIdx.x;
    const int lane = tid & 63, wv = tid >> 6;
    const int l15 = lane & 15, sub = lane >> 4;
    const int r0 = blockIdx.x * 64;

    // stage E chunk 0 via global_load_lds (1KB per wave-issue)
    {
        char* lb = (char*)Eb[0];
#pragma unroll
        for (int i = 0; i < 8; ++i) {
            int off = wv * 8192 + i * 1024;
            gload16(Eimg + off + lane * 16, lb + off);
        }
    }
    // stage X tile with in-register f32 -> bf16 h/l conversion
#pragma unroll
    for (int i = 0; i < 8; ++i) {
        int ci = tid + i * 256;
        int q = ci >> 6, r = ci & 63;
        const float* src = X + (size_t)(r0 + r) * DIM + q * 8;
        unsigned short h[8], l[8];
#pragma unroll
        for (int j = 0; j < 8; ++j) {
            float v = src[j];
            h[j] = bf16rne(v);
            float hf = __uint_as_float((unsigned)h[j] << 16);
            l[j] = bf16rne(v - hf);
        }
        short8x H, L;
#pragma unroll
        for (int j = 0; j < 8; ++j) { H[j] = (short)h[j]; L[j] = (short)l[j]; }
        *(short8x*)((char*)Xs + q * 1024 + r * 16) = H;
        *(short8x*)((char*)Xs + 32768 + q * 1024 + r * 16) = L;
    }

    float A_r[4][4];
#pragma unroll
    for (int f = 0; f < 4; ++f)
#pragma unroll
        for (int g = 0; g < 4; ++g) A_r[f][g] = Arow[r0 + f * 16 + sub * 4 + g];

    float r1v[4][4], r2v[4][4];
    int c1v[4][4];
#pragma unroll
    for (int f = 0; f < 4; ++f)
#pragma unroll
        for (int g = 0; g < 4; ++g) { r1v[f][g] = 3.4e38f; r2v[f][g] = 3.4e38f; c1v[f][g] = 0; }

    __syncthreads();

    for (int t = 0; t < 32; ++t) {
        f32x4 acc[4][4];
#pragma unroll
        for (int f = 0; f < 4; ++f)
#pragma unroll
            for (int c = 0; c < 4; ++c) acc[f][c] = (f32x4){0.f, 0.f, 0.f, 0.f};

#pragma unroll
        for (int S = 0; S < 8; ++S) {
            const int ci = t * 8 + S;            // ci & 1 == S & 1
            // prefetch next chunk into other buffer (clamped at end; harmless)
            {
                int cin = (ci + 1 > 255) ? 255 : ci + 1;
                const char* ech = Eimg + (size_t)cin * 32768;
                char* lb = (char*)Eb[(S + 1) & 1];
#pragma unroll
                for (int i = 0; i < 8; ++i) {
                    int off = wv * 8192 + i * 1024;
                    gload16(ech + off + lane * 16, lb + off);
                }
            }
            const char* xb = (const char*)Xs;
            const char* eb = (const char*)Eb[S & 1];
            short8x ah[4], al[4], ehh[4], ell[4];
#pragma unroll
            for (int f = 0; f < 4; ++f) {
                int off = (S * 4 + sub) * 1024 + f * 256 + l15 * 16;
                ah[f] = *(const short8x*)(xb + off);
                al[f] = *(const short8x*)(xb + 32768 + off);
            }
#pragma unroll
            for (int c = 0; c < 4; ++c) {
                int off = sub * 4096 + wv * 1024 + c * 256 + l15 * 16;
                ehh[c] = *(const short8x*)(eb + off);
                ell[c] = *(const short8x*)(eb + 16384 + off);
            }
#pragma unroll
            for (int f = 0; f < 4; ++f)
#pragma unroll
                for (int c = 0; c < 4; ++c) {
                    f32x4 a = acc[f][c];
                    a = __builtin_amdgcn_mfma_f32_16x16x32_bf16(al[f], ehh[c], a, 0, 0, 0);
                    a = __builtin_amdgcn_mfma_f32_16x16x32_bf16(ah[f], ell[c], a, 0, 0, 0);
                    a = __builtin_amdgcn_mfma_f32_16x16x32_bf16(ah[f], ehh[c], a, 0, 0, 0);
                    acc[f][c] = a;
                }
            __syncthreads();
        }

        // fold tile scores into running top-2 (in-lane; codes ascend with t,cf -> strict < ties OK)
        const int cbase = t * 256 + wv * 64 + l15;
#pragma unroll
        for (int f = 0; f < 4; ++f)
#pragma unroll
            for (int g = 0; g < 4; ++g) {
                float v0 = fmaf(-2.0f, acc[f][0][g], A_r[f][g]);
                float v1 = fmaf(-2.0f, acc[f][1][g], A_r[f][g]);
                float v2 = fmaf(-2.0f, acc[f][2][g], A_r[f][g]);
                float v3 = fmaf(-2.0f, acc[f][3][g], A_r[f][g]);
                float m01 = fminf(v0, v1), M01 = fmaxf(v0, v1);
                float m23 = fminf(v2, v3), M23 = fmaxf(v2, v3);
                int cc01 = (v1 < v0) ? cbase + 16 : cbase;
                int cc23 = (v3 < v2) ? cbase + 48 : cbase + 32;
                float t1 = fminf(m01, m23);
                float t2 = fminf(fmaxf(m01, m23), fminf(M01, M23));
                int tc1 = (m23 < m01) ? cc23 : cc01;
                bool upd = (t1 < r1v[f][g]);
                r2v[f][g] = upd ? fminf(r1v[f][g], t2) : fminf(r2v[f][g], t1);
                c1v[f][g] = upd ? tc1 : c1v[f][g];
                r1v[f][g] = upd ? t1 : r1v[f][g];
            }
    }

    // butterfly across the 16 code-lanes within wave, stash per-wave result
#pragma unroll
    for (int f = 0; f < 4; ++f)
#pragma unroll
        for (int g = 0; g < 4; ++g) {
            u64 k1 = ((u64)fkey(r1v[f][g]) << 32) | (unsigned)c1v[f][g];
            u64 k2 = ((u64)fkey(r2v[f][g]) << 32);
#pragma unroll
            for (int m = 1; m < 16; m <<= 1) {
                u64 o1 = __shfl_xor(k1, m, 64);
                u64 o2 = __shfl_xor(k2, m, 64);
                u64 mx = umax64(k1, o1);
                k1 = umin64(k1, o1);
                k2 = umin64(umin64(k2, o2), mx);
            }
            if (l15 == 0) {
                int row64 = f * 16 + sub * 4 + g;
                red[wv][row64][0] = k1;
                red[wv][row64][1] = k2;
            }
        }
    __syncthreads();
    if (tid < 64) {
        u64 K1 = red[0][tid][0], K2 = red[0][tid][1];
#pragma unroll
        for (int w = 1; w < 4; ++w) {
            u64 o1 = red[w][tid][0], o2 = red[w][tid][1];
            u64 mx = umax64(K1, o1);
            K1 = umin64(K1, o1);
            K2 = umin64(umin64(K2, o2), mx);
        }
        int r = r0 + tid;
        ws_idx[r] = (int)(unsigned)(K1 & 0xffffffffull);
        float s1 = fkeyinv((unsigned)(K1 >> 32));
        float s2 = fkeyinv((unsigned)(K2 >> 32));
        if (s2 - s1 < FLAG_GAP) {
            keybuf[r] = ~0ull;
            int slot = atomicAdd(flagcnt, 1);
            flaglist[slot] = r;
        }
    }
}

// ------- Kernel C: fp64 np-semantics refine; task = (16 rows, 2048-code range) -------
__global__ __launch_bounds__(256) void vq_refine_np(
    const float* __restrict__ X, const float* __restrict__ E,
    const float* __restrict__ Arow, u64* __restrict__ keybuf,
    const int* __restrict__ flaglist, const int* __restrict__ flagcnt) {
    __shared__ float xs[DIM][16];
    __shared__ float es[64][64];
    const int tid = threadIdx.x;
    const int tc = tid & 15, tr = tid >> 4;
    const int cnt = *flagcnt;
    const int ntasks = ((cnt + 15) >> 4) * 4;

    for (int task = blockIdx.x; task < ntasks; task += gridDim.x) {
        const int g = task >> 2, rng = task & 3;
        __syncthreads();
        // stage 16 flagged rows of X transposed
        {
            int slot = g * 16 + tr;
            int rowst = flaglist[slot < cnt ? slot : cnt - 1];
            const float* gX = X + (size_t)rowst * DIM + tc * 16;
#pragma unroll
            for (int w = 0; w < 4; ++w) {
                float4 v = *(const float4*)(gX + w * 4);
                int k = tc * 16 + w * 4;
                xs[k + 0][tr] = v.x;
                xs[k + 1][tr] = v.y;
                xs[k + 2][tr] = v.z;
                xs[k + 3][tr] = v.w;
            }
        }
        const int myslot = g * 16 + tr;
        const int myrow = flaglist[myslot < cnt ? myslot : cnt - 1];
        const float Ar = Arow[myrow];
        u64 K1 = ~0ull;

        for (int tile = 0; tile < 32; ++tile) {
            const int c0 = rng * 2048 + tile * 64;
            double acc0 = 0.0, acc1 = 0.0, acc2 = 0.0, acc3 = 0.0;
            for (int chunk = 0; chunk < 4; ++chunk) {
                __syncthreads();
                {
                    const int c = tid >> 2, q = tid & 3;
                    const float* gE = E + (size_t)(c0 + c) * DIM + chunk * 64 + q * 16;
#pragma unroll
                    for (int w = 0; w < 4; ++w) {
                        float4 v = *(const float4*)(gE + w * 4);
                        int kl = q * 16 + w * 4;
                        es[kl + 0][c] = v.x;
                        es[kl + 1][c] = v.y;
                        es[kl + 2][c] = v.z;
                        es[kl + 3][c] = v.w;
                    }
                }
                __syncthreads();
#pragma unroll 4
                for (int kl = 0; kl < 64; ++kl) {
                    double xd = (double)xs[chunk * 64 + kl][tr];
                    const float4 ev = *(const float4*)&es[kl][4 * tc];
                    acc0 = fma(xd, (double)ev.x, acc0);
                    acc1 = fma(xd, (double)ev.y, acc1);
                    acc2 = fma(xd, (double)ev.z, acc2);
                    acc3 = fma(xd, (double)ev.w, acc3);
                }
            }
            float s0 = fmaf(-2.0f, (float)acc0, Ar);
            float s1 = fmaf(-2.0f, (float)acc1, Ar);
            float s2 = fmaf(-2.0f, (float)acc2, Ar);
            float s3 = fmaf(-2.0f, (float)acc3, Ar);
            K1 = umin64(K1, ((u64)fkey(s0) << 32) | (unsigned)(c0 + 4 * tc + 0));
            K1 = umin64(K1, ((u64)fkey(s1) << 32) | (unsigned)(c0 + 4 * tc + 1));
            K1 = umin64(K1, ((u64)fkey(s2) << 32) | (unsigned)(c0 + 4 * tc + 2));
            K1 = umin64(K1, ((u64)fkey(s3) << 32) | (unsigned)(c0 + 4 * tc + 3));
        }
#pragma unroll
        for (int m = 1; m < 16; m <<= 1) K1 = umin64(K1, __shfl_xor(K1, m, 64));
        if (tc == 0 && myslot < cnt) atomicMin(keybuf + myrow, K1);
    }
}

// ------- Kernel C2: apply refined winners -------
__global__ void vq_apply(const u64* __restrict__ keybuf, const int* __restrict__ flaglist,
                         const int* __restrict__ flagcnt, int* __restrict__ ws_idx) {
    int s = blockIdx.x * 256 + threadIdx.x;
    if (s < *flagcnt) {
        int r = flaglist[s];
        ws_idx[r] = (int)(unsigned)(keybuf[r] & 0xffffffffull);
    }
}

// ---------------- Kernel D: gather quantized (ST-mimic), loss partials ----------------
__global__ void vq_out(const float* __restrict__ X, const float* __restrict__ E,
                       const int* __restrict__ ws_idx, float* __restrict__ out,
                       float* __restrict__ partials) {
    const int r = (blockIdx.x * 256 + threadIdx.x) >> 6;
    const int lane = threadIdx.x & 63;
    const int idx = ws_idx[r];
    float4 e = *((const float4*)(E + (size_t)idx * DIM + lane * 4));
    float4 x = *((const float4*)(X + (size_t)r * DIM + lane * 4));
    float dx = e.x - x.x, dy = e.y - x.y, dz = e.z - x.z, dw = e.w - x.w;
    float4 o;
    o.x = x.x + dx; o.y = x.y + dy; o.z = x.z + dz; o.w = x.w + dw;
    *((float4*)(out + (size_t)r * DIM + lane * 4)) = o;
    float s = dx * dx + dy * dy + dz * dz + dw * dw;
#pragma unroll
    for (int m = 1; m < 64; m <<= 1) s += __shfl_xor(s, m, 64);
    if (lane == 0) {
        partials[r] = s;
        out[OUT_IDX + r] = (float)idx;
    }
}

// ---------------- Kernel E: deterministic loss reduction ----------------
__global__ void vq_loss(const float* __restrict__ partials, float* __restrict__ out) {
    __shared__ double sred[4];
    double s = 0.0;
    for (int i = threadIdx.x; i < N_ROWS; i += 256) s += (double)partials[i];
#pragma unroll
    for (int m = 1; m < 64; m <<= 1) s += __shfl_xor(s, m, 64);
    if ((threadIdx.x & 63) == 0) sred[threadIdx.x >> 6] = s;
    __syncthreads();
    if (threadIdx.x == 0) {
        double t = sred[0] + sred[1] + sred[2] + sred[3];
        out[OUT_LOSS] = (float)(2.0 * t / (double)OUT_Q);
    }
}

extern "C" void kernel_launch(void* const* d_in, const int* in_sizes, int n_in,
                              void* d_out, int out_size, void* d_ws, size_t ws_size,
                              hipStream_t stream) {
    const float* X = (const float*)d_in[0];
    const float* E = (const float*)d_in[1];
    float* out = (float*)d_out;
    char* ws = (char*)d_ws;

    float* Arow = (float*)(ws + WS_AROW);
    int* idx = (int*)(ws + WS_IDX);
    int* list = (int*)(ws + WS_LIST);
    int* cnt = (int*)(ws + WS_CNT);
    u64* keys = (u64*)(ws + WS_KEYS);
    float* part = (float*)(ws + WS_PART);
    // E bf16 image (8MB): prefer ws; fall back to d_out scratch (overwritten by vq_out later)
    char* eimg = (ws_size >= (size_t)(WS_EIMG + 8 * 1024 * 1024)) ? (ws + WS_EIMG) : (char*)d_out;

    hipMemsetAsync(cnt, 0, sizeof(int), stream);
    vq_prepE<<<1024, 256, 0, stream>>>(E, eimg);
    vq_rowA<<<N_ROWS / 4, 256, 0, stream>>>(X, Arow);
    vq_argmin<<<N_ROWS / 64, 256, 0, stream>>>(X, eimg, Arow, idx, list, cnt, keys);
    vq_refine_np<<<1024, 256, 0, stream>>>(X, E, Arow, keys, list, cnt);
    vq_apply<<<128, 256, 0, stream>>>(keys, list, cnt, idx);
    vq_out<<<N_ROWS / 4, 256, 0, stream>>>(X, E, idx, out, part);
    vq_loss<<<1, 256, 0, stream>>>(part, out);
}

// Round 5
// 976.910 us; speedup vs baseline: 5.0486x; 1.4012x over previous
//
#include <hip/hip_runtime.h>

#define N_ROWS 32768
#define DIM 256
#define N_CODES 8192
#define OUT_Q 8388608        // N_ROWS*DIM
#define OUT_LOSS 8388608
#define OUT_IDX 8388609
#define FLAG_GAP 7e-5f       // >= 2 grid cells (g=3.05e-5) + 2*split-err (2.4e-6) -> safe
#define CAND_CAP 262144

// ws layout (bytes) — total 786688, same as round-4 proven footprint
#define WS_AROW 0            // 32768 f32
#define WS_IDX  131072       // 32768 i32
#define WS_LIST 262144       // 32768 i32
#define WS_CNT  393216       // i32
#define WS_CCNT 393232       // i32
#define WS_S1   393472       // 32768 f32
#define WS_KEYS 524544       // 32768 u64
#define WS_PART 524544       // aliased onto KEYS (keys dead before vq_out writes partials)
#define WS_EIMG 1048576      // 8MB E-image if ws_size allows, else d_out scratch

typedef __attribute__((ext_vector_type(8))) short short8x;
typedef __attribute__((ext_vector_type(4))) float f32x4;
typedef unsigned long long u64;
#define AS1 __attribute__((address_space(1)))
#define AS3 __attribute__((address_space(3)))

__device__ __forceinline__ u64 umin64(u64 a, u64 b) { return a < b ? a : b; }
__device__ __forceinline__ u64 umax64(u64 a, u64 b) { return a > b ? a : b; }
// order-preserving float->uint map
__device__ __forceinline__ unsigned fkey(float f) {
    unsigned b = __float_as_uint(f);
    return b ^ (unsigned)(((int)b >> 31) | 0x80000000);
}
__device__ __forceinline__ float fkeyinv(unsigned u) {
    unsigned b = (u >> 31) ? (u ^ 0x80000000u) : ~u;
    return __uint_as_float(b);
}
__device__ __forceinline__ unsigned short bf16rne(float f) {
    unsigned u = __float_as_uint(f);
    return (unsigned short)((u + 0x7fff + ((u >> 16) & 1)) >> 16);
}
__device__ __forceinline__ void gload16(const void* g, void* l) {
    __builtin_amdgcn_global_load_lds((const AS1 unsigned int*)g, (AS3 unsigned int*)l, 16, 0, 0);
}

// ---------------- Kernel P: E -> bf16 h/l split, frag-linear chunk images ----------------
__global__ void vq_prepE(const float* __restrict__ E, char* __restrict__ Eimg) {
    int t = blockIdx.x * 256 + threadIdx.x;   // 0..262143
    int cb = t >> 10;
    int u = t & 1023;
    int sub = u >> 8, code = u & 255;
    int tile = cb >> 3, S = cb & 7;
    const float* src = E + (size_t)(tile * 256 + code) * DIM + S * 32 + sub * 8;
    unsigned short h[8], l[8];
#pragma unroll
    for (int j = 0; j < 8; ++j) {
        float v = src[j];
        h[j] = bf16rne(v);
        float hf = __uint_as_float((unsigned)h[j] << 16);
        l[j] = bf16rne(v - hf);
    }
    short8x H, L;
#pragma unroll
    for (int j = 0; j < 8; ++j) { H[j] = (short)h[j]; L[j] = (short)l[j]; }
    char* dst = Eimg + (size_t)cb * 32768 + sub * 4096 + code * 16;
    *(short8x*)dst = H;
    *(short8x*)(dst + 16384) = L;
}

// ---------------- Kernel A: per-row ||x||^2 in fp64 -> fp32 ----------------
__global__ void vq_rowA(const float* __restrict__ X, float* __restrict__ Arow) {
    int row = blockIdx.x * 4 + (threadIdx.x >> 6);
    int lane = threadIdx.x & 63;
    const float4 v = *((const float4*)(X + (size_t)row * DIM + lane * 4));
    double s = (double)v.x * v.x + (double)v.y * v.y + (double)v.z * v.z + (double)v.w * v.w;
#pragma unroll
    for (int m = 1; m < 64; m <<= 1) s += __shfl_xor(s, m, 64);
    if (lane == 0) Arow[row] = (float)s;
}

// ------- Kernel B: MFMA split-bf16 distance scan.
//   MODE 0: all rows, top-2 argmin + flag + s1 store.
//   MODE 1: flagged rows (via flaglist), emit candidates with score <= s1+FLAG_GAP.
template <int MODE>
__global__ __launch_bounds__(256, 1) void vq_scan(
    const float* __restrict__ X, const char* __restrict__ Eimg,
    const float* __restrict__ Arow, int* __restrict__ ws_idx,
    int* __restrict__ flaglist, int* __restrict__ flagcnt,
    u64* __restrict__ keybuf, float* __restrict__ s1buf,
    unsigned* __restrict__ cand, int* __restrict__ candcnt) {
    __shared__ unsigned short Xs[32768];     // 64KB: h plane [0,32KB), l plane [32KB,64KB)
    __shared__ unsigned short Eb[2][16384];  // 2 x 32KB double-buffered E chunk
    __shared__ u64 red[4][64][2];            // cross-wave top-2 merge (MODE 0)
    __shared__ int rows_s[64];               // gathered row ids (MODE 1)

    const int tid = threadIdx.x;
    const int lane = tid & 63, wv = tid >> 6;
    const int l15 = lane & 15, sub = lane >> 4;

    const int cnt = (MODE == 1) ? *flagcnt : 0;

    float r1v[4][4], r2v[4][4];
    int c1v[4][4];
    if constexpr (MODE == 0) {
#pragma unroll
        for (int f = 0; f < 4; ++f)
#pragma unroll
            for (int g = 0; g < 4; ++g) { r1v[f][g] = 3.4e38f; r2v[f][g] = 3.4e38f; c1v[f][g] = 0; }
    }

    int grp = blockIdx.x;
    int r0 = grp * 64;
    while (true) {
        if constexpr (MODE == 1) {
            if (grp * 64 >= cnt) break;
            __syncthreads();   // previous iteration's readers of Xs/rows_s done
            if (tid < 64) {
                int s = grp * 64 + tid;
                rows_s[tid] = flaglist[s < cnt ? s : cnt - 1];
            }
            __syncthreads();
        }

        // issue E chunk 0 into Eb[0]
        {
            char* lb = (char*)Eb[0];
#pragma unroll
            for (int i = 0; i < 8; ++i) {
                int off = wv * 8192 + i * 1024;
                gload16(Eimg + off + lane * 16, lb + off);
            }
        }
        // stage X tile with in-register f32 -> bf16 h/l conversion
#pragma unroll
        for (int i = 0; i < 8; ++i) {
            int ci = tid + i * 256;
            int q = ci >> 6, r = ci & 63;
            int grow = (MODE == 1) ? rows_s[r] : r0 + r;
            const float* src = X + (size_t)grow * DIM + q * 8;
            unsigned short h[8], l[8];
#pragma unroll
            for (int j = 0; j < 8; ++j) {
                float v = src[j];
                h[j] = bf16rne(v);
                float hf = __uint_as_float((unsigned)h[j] << 16);
                l[j] = bf16rne(v - hf);
            }
            short8x H, L;
#pragma unroll
            for (int j = 0; j < 8; ++j) { H[j] = (short)h[j]; L[j] = (short)l[j]; }
            *(short8x*)((char*)Xs + q * 1024 + r * 16) = H;
            *(short8x*)((char*)Xs + 32768 + q * 1024 + r * 16) = L;
        }

        float A_r[4][4], s1v[4][4];
        int rid[4][4];
#pragma unroll
        for (int f = 0; f < 4; ++f)
#pragma unroll
            for (int g = 0; g < 4; ++g) {
                int rr = (MODE == 1) ? rows_s[f * 16 + sub * 4 + g] : r0 + f * 16 + sub * 4 + g;
                A_r[f][g] = Arow[rr];
                if constexpr (MODE == 1) { s1v[f][g] = s1buf[rr]; rid[f][g] = rr; }
            }

        __syncthreads();

        for (int t = 0; t < 32; ++t) {
            f32x4 acc[4][4];
#pragma unroll
            for (int f = 0; f < 4; ++f)
#pragma unroll
                for (int c = 0; c < 4; ++c) acc[f][c] = (f32x4){0.f, 0.f, 0.f, 0.f};

#pragma unroll
            for (int S = 0; S < 8; ++S) {
                const int ci = t * 8 + S;
                if (ci < 255) {   // prefetch next chunk into other buffer
                    const char* ech = Eimg + (size_t)(ci + 1) * 32768;
                    char* lb = (char*)Eb[(S + 1) & 1];
#pragma unroll
                    for (int i = 0; i < 8; ++i) {
                        int off = wv * 8192 + i * 1024;
                        gload16(ech + off + lane * 16, lb + off);
                    }
                }
                const char* xb = (const char*)Xs;
                const char* eb = (const char*)Eb[S & 1];
                short8x ah[4], al[4], ehh[4], ell[4];
#pragma unroll
                for (int f = 0; f < 4; ++f) {
                    int off = (S * 4 + sub) * 1024 + f * 256 + l15 * 16;
                    ah[f] = *(const short8x*)(xb + off);
                    al[f] = *(const short8x*)(xb + 32768 + off);
                }
#pragma unroll
                for (int c = 0; c < 4; ++c) {
                    int off = sub * 4096 + wv * 1024 + c * 256 + l15 * 16;
                    ehh[c] = *(const short8x*)(eb + off);
                    ell[c] = *(const short8x*)(eb + 16384 + off);
                }
#pragma unroll
                for (int f = 0; f < 4; ++f)
#pragma unroll
                    for (int c = 0; c < 4; ++c) {
                        f32x4 a = acc[f][c];
                        a = __builtin_amdgcn_mfma_f32_16x16x32_bf16(al[f], ehh[c], a, 0, 0, 0);
                        a = __builtin_amdgcn_mfma_f32_16x16x32_bf16(ah[f], ell[c], a, 0, 0, 0);
                        a = __builtin_amdgcn_mfma_f32_16x16x32_bf16(ah[f], ehh[c], a, 0, 0, 0);
                        acc[f][c] = a;
                    }
                __syncthreads();
            }

            const int cbase = t * 256 + wv * 64 + l15;
            if constexpr (MODE == 0) {
                // fold tile scores into running top-2
#pragma unroll
                for (int f = 0; f < 4; ++f)
#pragma unroll
                    for (int g = 0; g < 4; ++g) {
                        float v0 = fmaf(-2.0f, acc[f][0][g], A_r[f][g]);
                        float v1 = fmaf(-2.0f, acc[f][1][g], A_r[f][g]);
                        float v2 = fmaf(-2.0f, acc[f][2][g], A_r[f][g]);
                        float v3 = fmaf(-2.0f, acc[f][3][g], A_r[f][g]);
                        float m01 = fminf(v0, v1), M01 = fmaxf(v0, v1);
                        float m23 = fminf(v2, v3), M23 = fmaxf(v2, v3);
                        int cc01 = (v1 < v0) ? cbase + 16 : cbase;
                        int cc23 = (v3 < v2) ? cbase + 48 : cbase + 32;
                        float t1 = fminf(m01, m23);
                        float t2 = fminf(fmaxf(m01, m23), fminf(M01, M23));
                        int tc1 = (m23 < m01) ? cc23 : cc01;
                        bool upd = (t1 < r1v[f][g]);
                        r2v[f][g] = upd ? fminf(r1v[f][g], t2) : fminf(r2v[f][g], t1);
                        c1v[f][g] = upd ? tc1 : c1v[f][g];
                        r1v[f][g] = upd ? t1 : r1v[f][g];
                    }
            } else {
                // emit candidates: score <= s1 + FLAG_GAP
#pragma unroll
                for (int f = 0; f < 4; ++f)
#pragma unroll
                    for (int g = 0; g < 4; ++g) {
                        float thr = s1v[f][g] + FLAG_GAP;
#pragma unroll
                        for (int c = 0; c < 4; ++c) {
                            float v = fmaf(-2.0f, acc[f][c][g], A_r[f][g]);
                            if (v <= thr) {
                                int slot = atomicAdd(candcnt, 1);
                                if (slot < CAND_CAP)
                                    cand[slot] = ((unsigned)rid[f][g] << 13) |
                                                 (unsigned)(cbase + c * 16);
                            }
                        }
                    }
            }
        }

        if constexpr (MODE == 0) break;
        else grp += gridDim.x;
    }

    if constexpr (MODE == 0) {
        // butterfly across the 16 code-lanes within wave, stash per-wave result
#pragma unroll
        for (int f = 0; f < 4; ++f)
#pragma unroll
            for (int g = 0; g < 4; ++g) {
                u64 k1 = ((u64)fkey(r1v[f][g]) << 32) | (unsigned)c1v[f][g];
                u64 k2 = ((u64)fkey(r2v[f][g]) << 32);
#pragma unroll
                for (int m = 1; m < 16; m <<= 1) {
                    u64 o1 = __shfl_xor(k1, m, 64);
                    u64 o2 = __shfl_xor(k2, m, 64);
                    u64 mx = umax64(k1, o1);
                    k1 = umin64(k1, o1);
                    k2 = umin64(umin64(k2, o2), mx);
                }
                if (l15 == 0) {
                    int row64 = f * 16 + sub * 4 + g;
                    red[wv][row64][0] = k1;
                    red[wv][row64][1] = k2;
                }
            }
        __syncthreads();
        if (tid < 64) {
            u64 K1 = red[0][tid][0], K2 = red[0][tid][1];
#pragma unroll
            for (int w = 1; w < 4; ++w) {
                u64 o1 = red[w][tid][0], o2 = red[w][tid][1];
                u64 mx = umax64(K1, o1);
                K1 = umin64(K1, o1);
                K2 = umin64(umin64(K2, o2), mx);
            }
            int r = r0 + tid;
            ws_idx[r] = (int)(unsigned)(K1 & 0xffffffffull);
            float s1 = fkeyinv((unsigned)(K1 >> 32));
            float s2 = fkeyinv((unsigned)(K2 >> 32));
            s1buf[r] = s1;
            if (s2 - s1 < FLAG_GAP) {
                keybuf[r] = ~0ull;
                int slot = atomicAdd(flagcnt, 1);
                flaglist[slot] = r;
            }
        }
    }
}

// ------- Kernel C: fp64 np-semantics scoring of candidates, atomicMin merge -------
__global__ void vq_refine_cand(const float* __restrict__ X, const float* __restrict__ E,
                               const float* __restrict__ Arow, u64* __restrict__ keybuf,
                               const unsigned* __restrict__ cand,
                               const int* __restrict__ candcnt) {
    int cnt2 = *candcnt;
    cnt2 = cnt2 < CAND_CAP ? cnt2 : CAND_CAP;
    const int gw = (blockIdx.x * 256 + threadIdx.x) >> 6;   // global wave id
    const int nw = gridDim.x * 4;
    const int lane = threadIdx.x & 63;
    for (int i = gw; i < cnt2; i += nw) {
        unsigned p = cand[i];
        int row = (int)(p >> 13), code = (int)(p & 8191);
        float4 xv = *(const float4*)(X + (size_t)row * DIM + lane * 4);
        float4 ev = *(const float4*)(E + (size_t)code * DIM + lane * 4);
        double s = (double)xv.x * ev.x + (double)xv.y * ev.y +
                   (double)xv.z * ev.z + (double)xv.w * ev.w;
#pragma unroll
        for (int m = 1; m < 64; m <<= 1) s += __shfl_xor(s, m, 64);
        if (lane == 0) {
            float m32 = (float)s;
            float scr = fmaf(-2.0f, m32, Arow[row]);
            u64 key = ((u64)fkey(scr) << 32) | (unsigned)code;
            atomicMin(keybuf + row, key);
        }
    }
}

// ------- Kernel C2: apply refined winners -------
__global__ void vq_apply(const u64* __restrict__ keybuf, const int* __restrict__ flaglist,
                         const int* __restrict__ flagcnt, int* __restrict__ ws_idx) {
    int s = blockIdx.x * 256 + threadIdx.x;
    if (s < *flagcnt) {
        int r = flaglist[s];
        ws_idx[r] = (int)(unsigned)(keybuf[r] & 0xffffffffull);
    }
}

// ---------------- Kernel D: gather quantized (ST-mimic), loss partials ----------------
__global__ void vq_out(const float* __restrict__ X, const float* __restrict__ E,
                       const int* __restrict__ ws_idx, float* __restrict__ out,
                       float* __restrict__ partials) {
    const int r = (blockIdx.x * 256 + threadIdx.x) >> 6;
    const int lane = threadIdx.x & 63;
    const int idx = ws_idx[r];
    float4 e = *((const float4*)(E + (size_t)idx * DIM + lane * 4));
    float4 x = *((const float4*)(X + (size_t)r * DIM + lane * 4));
    float dx = e.x - x.x, dy = e.y - x.y, dz = e.z - x.z, dw = e.w - x.w;
    float4 o;
    o.x = x.x + dx; o.y = x.y + dy; o.z = x.z + dz; o.w = x.w + dw;
    *((float4*)(out + (size_t)r * DIM + lane * 4)) = o;
    float s = dx * dx + dy * dy + dz * dz + dw * dw;
#pragma unroll
    for (int m = 1; m < 64; m <<= 1) s += __shfl_xor(s, m, 64);
    if (lane == 0) {
        partials[r] = s;
        out[OUT_IDX + r] = (float)idx;
    }
}

// ---------------- Kernel E: deterministic loss reduction ----------------
__global__ void vq_loss(const float* __restrict__ partials, float* __restrict__ out) {
    __shared__ double sred[4];
    double s = 0.0;
    for (int i = threadIdx.x; i < N_ROWS; i += 256) s += (double)partials[i];
#pragma unroll
    for (int m = 1; m < 64; m <<= 1) s += __shfl_xor(s, m, 64);
    if ((threadIdx.x & 63) == 0) sred[threadIdx.x >> 6] = s;
    __syncthreads();
    if (threadIdx.x == 0) {
        double t = sred[0] + sred[1] + sred[2] + sred[3];
        out[OUT_LOSS] = (float)(2.0 * t / (double)OUT_Q);
    }
}

extern "C" void kernel_launch(void* const* d_in, const int* in_sizes, int n_in,
                              void* d_out, int out_size, void* d_ws, size_t ws_size,
                              hipStream_t stream) {
    const float* X = (const float*)d_in[0];
    const float* E = (const float*)d_in[1];
    float* out = (float*)d_out;
    char* ws = (char*)d_ws;

    float* Arow = (float*)(ws + WS_AROW);
    int* idx = (int*)(ws + WS_IDX);
    int* list = (int*)(ws + WS_LIST);
    int* cnt = (int*)(ws + WS_CNT);
    int* ccnt = (int*)(ws + WS_CCNT);
    float* s1buf = (float*)(ws + WS_S1);
    u64* keys = (u64*)(ws + WS_KEYS);
    float* part = (float*)(ws + WS_PART);   // aliased onto keys (dead by then)
    // E bf16 image (8MB): prefer ws; fall back to d_out scratch (overwritten by vq_out later)
    char* eimg = (ws_size >= (size_t)(WS_EIMG + 8 * 1024 * 1024)) ? (ws + WS_EIMG) : (char*)d_out;
    // candidate list: d_out bytes [16MB, 17MB) — inside quantized region, overwritten by vq_out
    unsigned* cand = (unsigned*)((char*)d_out + (16 << 20));

    hipMemsetAsync(ws + WS_CNT, 0, 32, stream);   // zero flagcnt + candcnt
    vq_prepE<<<1024, 256, 0, stream>>>(E, eimg);
    vq_rowA<<<N_ROWS / 4, 256, 0, stream>>>(X, Arow);
    vq_scan<0><<<N_ROWS / 64, 256, 0, stream>>>(X, eimg, Arow, idx, list, cnt, keys, s1buf,
                                                cand, ccnt);
    vq_scan<1><<<256, 256, 0, stream>>>(X, eimg, Arow, idx, list, cnt, keys, s1buf, cand, ccnt);
    vq_refine_cand<<<1024, 256, 0, stream>>>(X, E, Arow, keys, cand, ccnt);
    vq_apply<<<128, 256, 0, stream>>>(keys, list, cnt, idx);
    vq_out<<<N_ROWS / 4, 256, 0, stream>>>(X, E, idx, out, part);
    vq_loss<<<1, 256, 0, stream>>>(part, out);
}

// Round 6
// 671.713 us; speedup vs baseline: 7.3425x; 1.4544x over previous
//
#include <hip/hip_runtime.h>

#define N_ROWS 32768
#define DIM 256
#define N_CODES 8192
#define OUT_Q 8388608        // N_ROWS*DIM
#define OUT_LOSS 8388608
#define OUT_IDX 8388609
#define FLAG_GAP 7e-5f       // >= 2 grid cells (g=3.05e-5) + 2*split-err -> safe
#define CAND_CAP 262144

// ws layout (bytes)
#define WS_AROW 0            // 32768 f32
#define WS_IDX  131072       // 32768 i32
#define WS_LIST 262144       // 32768 i32
#define WS_CNT  393216       // i32
#define WS_CCNT 393232       // i32
#define WS_S1   393472       // 32768 f32
#define WS_KEYS 524544       // 32768 u64
#define WS_PART 524544       // aliased onto KEYS (keys dead before vq_out writes partials)
#define WS_EIMG 1048576      // 8MB E-image if ws_size allows, else d_out scratch

typedef __attribute__((ext_vector_type(8))) short short8x;
typedef __attribute__((ext_vector_type(4))) float f32x4;
typedef unsigned long long u64;
#define AS1 __attribute__((address_space(1)))
#define AS3 __attribute__((address_space(3)))

__device__ __forceinline__ u64 umin64(u64 a, u64 b) { return a < b ? a : b; }
__device__ __forceinline__ u64 umax64(u64 a, u64 b) { return a > b ? a : b; }
// order-preserving float->uint map
__device__ __forceinline__ unsigned fkey(float f) {
    unsigned b = __float_as_uint(f);
    return b ^ (unsigned)(((int)b >> 31) | 0x80000000);
}
__device__ __forceinline__ float fkeyinv(unsigned u) {
    unsigned b = (u >> 31) ? (u ^ 0x80000000u) : ~u;
    return __uint_as_float(b);
}
__device__ __forceinline__ unsigned short bf16rne(float f) {
    unsigned u = __float_as_uint(f);
    return (unsigned short)((u + 0x7fff + ((u >> 16) & 1)) >> 16);
}
__device__ __forceinline__ void gload16(const void* g, void* l) {
    __builtin_amdgcn_global_load_lds((const AS1 unsigned int*)g, (AS3 unsigned int*)l, 16, 0, 0);
}

// ---------------- Kernel P: E -> bf16 h/l split, frag-linear chunk images ----------------
// 256 chunks (tile 0..31 x S 0..7) of 32KB; chunk = 256 codes x 32 k x {h,l}:
//   off = cb*32768 + plane*16384 + sub*4096 + code*16  (k = S*32 + sub*8 + j)
__global__ void vq_prepE(const float* __restrict__ E, char* __restrict__ Eimg) {
    int t = blockIdx.x * 256 + threadIdx.x;   // 0..262143
    int cb = t >> 10;
    int u = t & 1023;
    int sub = u >> 8, code = u & 255;
    int tile = cb >> 3, S = cb & 7;
    const float* src = E + (size_t)(tile * 256 + code) * DIM + S * 32 + sub * 8;
    unsigned short h[8], l[8];
#pragma unroll
    for (int j = 0; j < 8; ++j) {
        float v = src[j];
        h[j] = bf16rne(v);
        float hf = __uint_as_float((unsigned)h[j] << 16);
        l[j] = bf16rne(v - hf);
    }
    short8x H, L;
#pragma unroll
    for (int j = 0; j < 8; ++j) { H[j] = (short)h[j]; L[j] = (short)l[j]; }
    char* dst = Eimg + (size_t)cb * 32768 + sub * 4096 + code * 16;
    *(short8x*)dst = H;
    *(short8x*)(dst + 16384) = L;
}

// ---------------- Kernel A: per-row ||x||^2 in fp64 -> fp32 ----------------
__global__ void vq_rowA(const float* __restrict__ X, float* __restrict__ Arow) {
    int row = blockIdx.x * 4 + (threadIdx.x >> 6);
    int lane = threadIdx.x & 63;
    const float4 v = *((const float4*)(X + (size_t)row * DIM + lane * 4));
    double s = (double)v.x * v.x + (double)v.y * v.y + (double)v.z * v.z + (double)v.w * v.w;
#pragma unroll
    for (int m = 1; m < 64; m <<= 1) s += __shfl_xor(s, m, 64);
    if (lane == 0) Arow[row] = (float)s;
}

// ------- Kernel B: MFMA split-bf16 distance scan (512 thr, 8 waves, 2 waves/SIMD).
//   MODE 0: all rows, top-2 argmin + flag + s1 store. 1 group per block.
//   MODE 1: flagged rows; task = (group, 1024-code range); emit candidates <= s1+GAP.
template <int MODE>
__global__ __launch_bounds__(512, 1) void vq_scan(
    const float* __restrict__ X, const char* __restrict__ Eimg,
    const float* __restrict__ Arow, int* __restrict__ ws_idx,
    int* __restrict__ flaglist, int* __restrict__ flagcnt,
    u64* __restrict__ keybuf, float* __restrict__ s1buf,
    unsigned* __restrict__ cand, int* __restrict__ candcnt) {
    __shared__ unsigned short Xs[32768];     // 64KB: h plane [0,32KB), l plane [32KB,64KB)
    __shared__ unsigned short Eb[2][16384];  // 2 x 32KB double-buffered E chunk
    __shared__ int rows_s[64];               // gathered row ids (MODE 1)

    const int tid = threadIdx.x;
    const int lane = tid & 63, wv = tid >> 6;      // wv 0..7
    const int l15 = lane & 15, sub = lane >> 4;

    const int cnt = (MODE == 1) ? *flagcnt : 0;
    const int ntasks = (MODE == 1) ? ((cnt + 63) >> 6) * 8 : 0;

    float r1v[4][4], r2v[4][4];
    int c1v[4][4];
    if constexpr (MODE == 0) {
#pragma unroll
        for (int f = 0; f < 4; ++f)
#pragma unroll
            for (int g = 0; g < 4; ++g) { r1v[f][g] = 3.4e38f; r2v[f][g] = 3.4e38f; c1v[f][g] = 0; }
    }

    int task = blockIdx.x;
    while (true) {
        int grp, t0, t1, clast, r0;
        if constexpr (MODE == 1) {
            if (task >= ntasks) break;
            grp = task >> 3;
            int rng = task & 7;
            t0 = rng * 4; t1 = t0 + 4;
            clast = t1 * 8 - 1;
            r0 = 0;
            __syncthreads();   // previous task's readers of Xs/Eb/rows_s done
            if (tid < 64) {
                int s = grp * 64 + tid;
                rows_s[tid] = flaglist[s < cnt ? s : cnt - 1];
            }
            __syncthreads();
        } else {
            grp = blockIdx.x;
            t0 = 0; t1 = 32; clast = 255;
            r0 = grp * 64;
        }

        // issue first E chunk of range into its parity buffer (t0*8 is even -> Eb[0])
        {
            const char* ech = Eimg + (size_t)(t0 * 8) * 32768;
            char* lb = (char*)Eb[0];
#pragma unroll
            for (int i = 0; i < 4; ++i) {
                int off = wv * 4096 + i * 1024;
                gload16(ech + off + lane * 16, lb + off);
            }
        }
        // stage X tile with in-register f32 -> bf16 h/l conversion
#pragma unroll
        for (int i = 0; i < 4; ++i) {
            int ci = tid + i * 512;                // 0..2047
            int q = ci >> 6, r = ci & 63;
            int grow = (MODE == 1) ? rows_s[r] : r0 + r;
            const float* src = X + (size_t)grow * DIM + q * 8;
            unsigned short h[8], l[8];
#pragma unroll
            for (int j = 0; j < 8; ++j) {
                float v = src[j];
                h[j] = bf16rne(v);
                float hf = __uint_as_float((unsigned)h[j] << 16);
                l[j] = bf16rne(v - hf);
            }
            short8x H, L;
#pragma unroll
            for (int j = 0; j < 8; ++j) { H[j] = (short)h[j]; L[j] = (short)l[j]; }
            *(short8x*)((char*)Xs + q * 1024 + r * 16) = H;
            *(short8x*)((char*)Xs + 32768 + q * 1024 + r * 16) = L;
        }

        float A_r[4][4], s1v[4][4];
        int rid[4][4];
#pragma unroll
        for (int f = 0; f < 4; ++f)
#pragma unroll
            for (int g = 0; g < 4; ++g) {
                int rr = (MODE == 1) ? rows_s[f * 16 + sub * 4 + g] : r0 + f * 16 + sub * 4 + g;
                A_r[f][g] = Arow[rr];
                if constexpr (MODE == 1) { s1v[f][g] = s1buf[rr]; rid[f][g] = rr; }
            }

        __syncthreads();

        for (int t = t0; t < t1; ++t) {
            f32x4 acc[4][2];
#pragma unroll
            for (int f = 0; f < 4; ++f)
#pragma unroll
                for (int c = 0; c < 2; ++c) acc[f][c] = (f32x4){0.f, 0.f, 0.f, 0.f};

#pragma unroll
            for (int S = 0; S < 8; ++S) {
                const int ci = t * 8 + S;
                if (ci < clast) {   // prefetch next chunk into other buffer
                    const char* ech = Eimg + (size_t)(ci + 1) * 32768;
                    char* lb = (char*)Eb[(S + 1) & 1];
#pragma unroll
                    for (int i = 0; i < 4; ++i) {
                        int off = wv * 4096 + i * 1024;
                        gload16(ech + off + lane * 16, lb + off);
                    }
                }
                const char* xb = (const char*)Xs;
                const char* eb = (const char*)Eb[S & 1];
                short8x ah[4], al[4], ehh[2], ell[2];
#pragma unroll
                for (int f = 0; f < 4; ++f) {
                    int off = (S * 4 + sub) * 1024 + f * 256 + l15 * 16;
                    ah[f] = *(const short8x*)(xb + off);
                    al[f] = *(const short8x*)(xb + 32768 + off);
                }
#pragma unroll
                for (int c = 0; c < 2; ++c) {
                    int off = sub * 4096 + wv * 512 + c * 256 + l15 * 16;
                    ehh[c] = *(const short8x*)(eb + off);
                    ell[c] = *(const short8x*)(eb + 16384 + off);
                }
#pragma unroll
                for (int f = 0; f < 4; ++f)
#pragma unroll
                    for (int c = 0; c < 2; ++c) {
                        f32x4 a = acc[f][c];
                        a = __builtin_amdgcn_mfma_f32_16x16x32_bf16(al[f], ehh[c], a, 0, 0, 0);
                        a = __builtin_amdgcn_mfma_f32_16x16x32_bf16(ah[f], ell[c], a, 0, 0, 0);
                        a = __builtin_amdgcn_mfma_f32_16x16x32_bf16(ah[f], ehh[c], a, 0, 0, 0);
                        acc[f][c] = a;
                    }
                __syncthreads();
            }

            const int cbase = t * 256 + wv * 32 + l15;   // + c*16
            if constexpr (MODE == 0) {
#pragma unroll
                for (int f = 0; f < 4; ++f)
#pragma unroll
                    for (int g = 0; g < 4; ++g) {
                        float v0 = fmaf(-2.0f, acc[f][0][g], A_r[f][g]);
                        float v1 = fmaf(-2.0f, acc[f][1][g], A_r[f][g]);
                        float tt1 = fminf(v0, v1), tt2 = fmaxf(v0, v1);
                        int tc1 = (v1 < v0) ? cbase + 16 : cbase;
                        bool upd = (tt1 < r1v[f][g]);
                        r2v[f][g] = upd ? fminf(r1v[f][g], tt2) : fminf(r2v[f][g], tt1);
                        c1v[f][g] = upd ? tc1 : c1v[f][g];
                        r1v[f][g] = upd ? tt1 : r1v[f][g];
                    }
            } else {
#pragma unroll
                for (int f = 0; f < 4; ++f)
#pragma unroll
                    for (int g = 0; g < 4; ++g) {
                        float thr = s1v[f][g] + FLAG_GAP;
#pragma unroll
                        for (int c = 0; c < 2; ++c) {
                            float v = fmaf(-2.0f, acc[f][c][g], A_r[f][g]);
                            if (v <= thr) {
                                int slot = atomicAdd(candcnt, 1);
                                if (slot < CAND_CAP)
                                    cand[slot] = ((unsigned)rid[f][g] << 13) |
                                                 (unsigned)(cbase + c * 16);
                            }
                        }
                    }
            }
        }

        if constexpr (MODE == 0) break;
        else task += gridDim.x;
    }

    if constexpr (MODE == 0) {
        // butterfly across the 16 code-lanes within wave; merge via red aliased into Xs
        u64* red = (u64*)Xs;   // [8 waves][64 rows][2]; Xs dead after last tile barrier
#pragma unroll
        for (int f = 0; f < 4; ++f)
#pragma unroll
            for (int g = 0; g < 4; ++g) {
                u64 k1 = ((u64)fkey(r1v[f][g]) << 32) | (unsigned)c1v[f][g];
                u64 k2 = ((u64)fkey(r2v[f][g]) << 32);
#pragma unroll
                for (int m = 1; m < 16; m <<= 1) {
                    u64 o1 = __shfl_xor(k1, m, 64);
                    u64 o2 = __shfl_xor(k2, m, 64);
                    u64 mx = umax64(k1, o1);
                    k1 = umin64(k1, o1);
                    k2 = umin64(umin64(k2, o2), mx);
                }
                if (l15 == 0) {
                    int row64 = f * 16 + sub * 4 + g;
                    red[(wv * 64 + row64) * 2 + 0] = k1;
                    red[(wv * 64 + row64) * 2 + 1] = k2;
                }
            }
        __syncthreads();
        if (tid < 64) {
            u64 K1 = red[tid * 2 + 0], K2 = red[tid * 2 + 1];
#pragma unroll
            for (int w = 1; w < 8; ++w) {
                u64 o1 = red[(w * 64 + tid) * 2 + 0], o2 = red[(w * 64 + tid) * 2 + 1];
                u64 mx = umax64(K1, o1);
                K1 = umin64(K1, o1);
                K2 = umin64(umin64(K2, o2), mx);
            }
            int r = blockIdx.x * 64 + tid;
            ws_idx[r] = (int)(unsigned)(K1 & 0xffffffffull);
            float s1 = fkeyinv((unsigned)(K1 >> 32));
            float s2 = fkeyinv((unsigned)(K2 >> 32));
            s1buf[r] = s1;
            if (s2 - s1 < FLAG_GAP) {
                keybuf[r] = ~0ull;
                int slot = atomicAdd(flagcnt, 1);
                flaglist[slot] = r;
            }
        }
    }
}

// ------- Kernel C: fp64 np-semantics scoring of candidates, atomicMin merge -------
__global__ void vq_refine_cand(const float* __restrict__ X, const float* __restrict__ E,
                               const float* __restrict__ Arow, u64* __restrict__ keybuf,
                               const unsigned* __restrict__ cand,
                               const int* __restrict__ candcnt) {
    int cnt2 = *candcnt;
    cnt2 = cnt2 < CAND_CAP ? cnt2 : CAND_CAP;
    const int gw = (blockIdx.x * 256 + threadIdx.x) >> 6;   // global wave id
    const int nw = gridDim.x * 4;
    const int lane = threadIdx.x & 63;
    for (int i = gw; i < cnt2; i += nw) {
        unsigned p = cand[i];
        int row = (int)(p >> 13), code = (int)(p & 8191);
        float4 xv = *(const float4*)(X + (size_t)row * DIM + lane * 4);
        float4 ev = *(const float4*)(E + (size_t)code * DIM + lane * 4);
        double s = (double)xv.x * ev.x + (double)xv.y * ev.y +
                   (double)xv.z * ev.z + (double)xv.w * ev.w;
#pragma unroll
        for (int m = 1; m < 64; m <<= 1) s += __shfl_xor(s, m, 64);
        if (lane == 0) {
            float m32 = (float)s;
            float scr = fmaf(-2.0f, m32, Arow[row]);
            u64 key = ((u64)fkey(scr) << 32) | (unsigned)code;
            atomicMin(keybuf + row, key);
        }
    }
}

// ------- Kernel C2: apply refined winners -------
__global__ void vq_apply(const u64* __restrict__ keybuf, const int* __restrict__ flaglist,
                         const int* __restrict__ flagcnt, int* __restrict__ ws_idx) {
    int s = blockIdx.x * 256 + threadIdx.x;
    if (s < *flagcnt) {
        int r = flaglist[s];
        ws_idx[r] = (int)(unsigned)(keybuf[r] & 0xffffffffull);
    }
}

// ---------------- Kernel D: gather quantized (ST-mimic), loss partials ----------------
__global__ void vq_out(const float* __restrict__ X, const float* __restrict__ E,
                       const int* __restrict__ ws_idx, float* __restrict__ out,
                       float* __restrict__ partials) {
    const int r = (blockIdx.x * 256 + threadIdx.x) >> 6;
    const int lane = threadIdx.x & 63;
    const int idx = ws_idx[r];
    float4 e = *((const float4*)(E + (size_t)idx * DIM + lane * 4));
    float4 x = *((const float4*)(X + (size_t)r * DIM + lane * 4));
    float dx = e.x - x.x, dy = e.y - x.y, dz = e.z - x.z, dw = e.w - x.w;
    float4 o;
    o.x = x.x + dx; o.y = x.y + dy; o.z = x.z + dz; o.w = x.w + dw;
    *((float4*)(out + (size_t)r * DIM + lane * 4)) = o;
    float s = dx * dx + dy * dy + dz * dz + dw * dw;
#pragma unroll
    for (int m = 1; m < 64; m <<= 1) s += __shfl_xor(s, m, 64);
    if (lane == 0) {
        partials[r] = s;
        out[OUT_IDX + r] = (float)idx;
    }
}

// ---------------- Kernel E: deterministic loss reduction ----------------
__global__ void vq_loss(const float* __restrict__ partials, float* __restrict__ out) {
    __shared__ double sred[4];
    double s = 0.0;
    for (int i = threadIdx.x; i < N_ROWS; i += 256) s += (double)partials[i];
#pragma unroll
    for (int m = 1; m < 64; m <<= 1) s += __shfl_xor(s, m, 64);
    if ((threadIdx.x & 63) == 0) sred[threadIdx.x >> 6] = s;
    __syncthreads();
    if (threadIdx.x == 0) {
        double t = sred[0] + sred[1] + sred[2] + sred[3];
        out[OUT_LOSS] = (float)(2.0 * t / (double)OUT_Q);
    }
}

extern "C" void kernel_launch(void* const* d_in, const int* in_sizes, int n_in,
                              void* d_out, int out_size, void* d_ws, size_t ws_size,
                              hipStream_t stream) {
    const float* X = (const float*)d_in[0];
    const float* E = (const float*)d_in[1];
    float* out = (float*)d_out;
    char* ws = (char*)d_ws;

    float* Arow = (float*)(ws + WS_AROW);
    int* idx = (int*)(ws + WS_IDX);
    int* list = (int*)(ws + WS_LIST);
    int* cnt = (int*)(ws + WS_CNT);
    int* ccnt = (int*)(ws + WS_CCNT);
    float* s1buf = (float*)(ws + WS_S1);
    u64* keys = (u64*)(ws + WS_KEYS);
    float* part = (float*)(ws + WS_PART);   // aliased onto keys (dead by then)
    char* eimg = (ws_size >= (size_t)(WS_EIMG + 8 * 1024 * 1024)) ? (ws + WS_EIMG) : (char*)d_out;
    unsigned* cand = (unsigned*)((char*)d_out + (16 << 20));   // overwritten by vq_out later

    hipMemsetAsync(ws + WS_CNT, 0, 32, stream);   // zero flagcnt + candcnt
    vq_prepE<<<1024, 256, 0, stream>>>(E, eimg);
    vq_rowA<<<N_ROWS / 4, 256, 0, stream>>>(X, Arow);
    vq_scan<0><<<N_ROWS / 64, 512, 0, stream>>>(X, eimg, Arow, idx, list, cnt, keys, s1buf,
                                                cand, ccnt);
    vq_scan<1><<<512, 512, 0, stream>>>(X, eimg, Arow, idx, list, cnt, keys, s1buf, cand, ccnt);
    vq_refine_cand<<<1024, 256, 0, stream>>>(X, E, Arow, keys, cand, ccnt);
    vq_apply<<<128, 256, 0, stream>>>(keys, list, cnt, idx);
    vq_out<<<N_ROWS / 4, 256, 0, stream>>>(X, E, idx, out, part);
    vq_loss<<<1, 256, 0, stream>>>(part, out);
}

// Round 7
// 541.752 us; speedup vs baseline: 9.1039x; 1.2399x over previous
//
#include <hip/hip_runtime.h>

#define N_ROWS 32768
#define DIM 256
#define N_CODES 8192
#define OUT_Q 8388608        // N_ROWS*DIM
#define OUT_LOSS 8388608
#define OUT_IDX 8388609
#define FLAG_GAP 7e-5f       // >= 2 grid cells (g=3.05e-5) + 2*split-err -> safe
#define CAND_CAP 262144

// ws layout (bytes)
#define WS_AROW 0            // 32768 f32
#define WS_IDX  131072       // 32768 i32
#define WS_LIST 262144       // 32768 i32
#define WS_CNT  393216       // i32
#define WS_CCNT 393232       // i32
#define WS_S1   393472       // 32768 f32
#define WS_KEYS 524544       // 32768 u64
#define WS_PART 524544       // aliased onto KEYS (keys dead before vq_out writes partials)
#define WS_EIMG 1048576      // 8MB E-image if ws_size allows, else d_out scratch

typedef __attribute__((ext_vector_type(8))) short short8x;
typedef __attribute__((ext_vector_type(4))) float f32x4;
typedef unsigned long long u64;
#define AS1 __attribute__((address_space(1)))
#define AS3 __attribute__((address_space(3)))

__device__ __forceinline__ u64 umin64(u64 a, u64 b) { return a < b ? a : b; }
__device__ __forceinline__ u64 umax64(u64 a, u64 b) { return a > b ? a : b; }
// order-preserving float->uint map
__device__ __forceinline__ unsigned fkey(float f) {
    unsigned b = __float_as_uint(f);
    return b ^ (unsigned)(((int)b >> 31) | 0x80000000);
}
__device__ __forceinline__ float fkeyinv(unsigned u) {
    unsigned b = (u >> 31) ? (u ^ 0x80000000u) : ~u;
    return __uint_as_float(b);
}
__device__ __forceinline__ unsigned short bf16rne(float f) {
    unsigned u = __float_as_uint(f);
    return (unsigned short)((u + 0x7fff + ((u >> 16) & 1)) >> 16);
}
__device__ __forceinline__ void gload16(const void* g, void* l) {
    __builtin_amdgcn_global_load_lds((const AS1 unsigned int*)g, (AS3 unsigned int*)l, 16, 0, 0);
}

// ---------------- Kernel P: E -> bf16 h/l split, wave-private chunk images ----------------
// 256 chunks (tile 0..31 x S 0..7) of 32KB. Chunk = 8 wave-blocks of 4KB.
// Wave block w covers codes tile*256 + w*32 + c*16 + l15 (c 0..1, l15 0..15):
//   off_in_chunk = w*4096 + plane*2048 + sub*512 + c*256 + l15*16   (k = S*32 + sub*8 + j)
__global__ void vq_prepE(const float* __restrict__ E, char* __restrict__ Eimg) {
    int t = blockIdx.x * 256 + threadIdx.x;   // 0..262143
    int cb = t >> 10;
    int u = t & 1023;
    int w = u >> 7, v = u & 127;
    int sub = v >> 5, c = (v >> 4) & 1, l15 = v & 15;
    int tile = cb >> 3, S = cb & 7;
    const float* src = E + (size_t)(tile * 256 + w * 32 + c * 16 + l15) * DIM + S * 32 + sub * 8;
    unsigned short h[8], l[8];
#pragma unroll
    for (int j = 0; j < 8; ++j) {
        float vv = src[j];
        h[j] = bf16rne(vv);
        float hf = __uint_as_float((unsigned)h[j] << 16);
        l[j] = bf16rne(vv - hf);
    }
    short8x H, L;
#pragma unroll
    for (int j = 0; j < 8; ++j) { H[j] = (short)h[j]; L[j] = (short)l[j]; }
    char* dst = Eimg + (size_t)cb * 32768 + w * 4096 + sub * 512 + c * 256 + l15 * 16;
    *(short8x*)dst = H;
    *(short8x*)(dst + 2048) = L;
}

// ---------------- Kernel A: per-row ||x||^2 in fp64 -> fp32 ----------------
__global__ void vq_rowA(const float* __restrict__ X, float* __restrict__ Arow) {
    int row = blockIdx.x * 4 + (threadIdx.x >> 6);
    int lane = threadIdx.x & 63;
    const float4 v = *((const float4*)(X + (size_t)row * DIM + lane * 4));
    double s = (double)v.x * v.x + (double)v.y * v.y + (double)v.z * v.z + (double)v.w * v.w;
#pragma unroll
    for (int m = 1; m < 64; m <<= 1) s += __shfl_xor(s, m, 64);
    if (lane == 0) Arow[row] = (float)s;
}

// ------- Kernel B: MFMA split-bf16 distance scan, barrier-free main loop.
//   E staging is wave-private (4KB/chunk/wave, double-buffered) with counted vmcnt(4).
//   MODE 0: all rows, top-2 argmin + flag + s1 store. 1 group per block.
//   MODE 1: flagged rows; task = (group, 1024-code range); emit candidates <= s1+GAP.
template <int MODE>
__global__ __launch_bounds__(512, 1) void vq_scan(
    const float* __restrict__ X, const char* __restrict__ Eimg,
    const float* __restrict__ Arow, int* __restrict__ ws_idx,
    int* __restrict__ flaglist, int* __restrict__ flagcnt,
    u64* __restrict__ keybuf, float* __restrict__ s1buf,
    unsigned* __restrict__ cand, int* __restrict__ candcnt) {
    __shared__ unsigned short Xs[32768];   // 64KB: h plane [0,32KB), l plane [32KB,64KB)
    __shared__ unsigned short Eb[32768];   // 64KB: 2 bufs x 8 waves x 4KB, wave-private
    __shared__ int rows_s[64];             // gathered row ids (MODE 1)

    const int tid = threadIdx.x;
    const int lane = tid & 63, wv = tid >> 6;      // wv 0..7
    const int l15 = lane & 15, sub = lane >> 4;

    const int cnt = (MODE == 1) ? *flagcnt : 0;
    const int ntasks = (MODE == 1) ? ((cnt + 63) >> 6) * 8 : 0;

    char* const ebase = (char*)Eb + wv * 4096;     // this wave's staging base (+buf*32768)
    const char* const eimgw = Eimg + wv * 4096;

    float r1v[4][4], r2v[4][4];
    int c1v[4][4];
    if constexpr (MODE == 0) {
#pragma unroll
        for (int f = 0; f < 4; ++f)
#pragma unroll
            for (int g = 0; g < 4; ++g) { r1v[f][g] = 3.4e38f; r2v[f][g] = 3.4e38f; c1v[f][g] = 0; }
    }

    int task = blockIdx.x;
    while (true) {
        int t0, t1, r0;
        if constexpr (MODE == 1) {
            if (task >= ntasks) break;
            int grp = task >> 3;
            int rng = task & 7;
            t0 = rng * 4; t1 = t0 + 4;
            r0 = 0;
            __syncthreads();   // all waves done with previous task's Xs/rows_s
            if (tid < 64) {
                int s = grp * 64 + tid;
                rows_s[tid] = flaglist[s < cnt ? s : cnt - 1];
            }
            __syncthreads();
        } else {
            t0 = 0; t1 = 32;
            r0 = blockIdx.x * 64;
        }
        const int cend = t1 * 8;

        // issue first E chunk of range into its parity buffer (wave-private)
        {
            const int ci = t0 * 8;
            const char* src = eimgw + (size_t)ci * 32768 + lane * 16;
            char* dst = ebase + (ci & 1) * 32768;
#pragma unroll
            for (int i = 0; i < 4; ++i) gload16(src + i * 1024, dst + i * 1024);
        }
        // stage X tile with in-register f32 -> bf16 h/l conversion
#pragma unroll
        for (int i = 0; i < 4; ++i) {
            int ci = tid + i * 512;                // 0..2047
            int q = ci >> 6, r = ci & 63;
            int grow = (MODE == 1) ? rows_s[r] : r0 + r;
            const float* src = X + (size_t)grow * DIM + q * 8;
            unsigned short h[8], l[8];
#pragma unroll
            for (int j = 0; j < 8; ++j) {
                float v = src[j];
                h[j] = bf16rne(v);
                float hf = __uint_as_float((unsigned)h[j] << 16);
                l[j] = bf16rne(v - hf);
            }
            short8x H, L;
#pragma unroll
            for (int j = 0; j < 8; ++j) { H[j] = (short)h[j]; L[j] = (short)l[j]; }
            *(short8x*)((char*)Xs + q * 1024 + r * 16) = H;
            *(short8x*)((char*)Xs + 32768 + q * 1024 + r * 16) = L;
        }

        float A_r[4][4], s1v[4][4];
        int rid[4][4];
#pragma unroll
        for (int f = 0; f < 4; ++f)
#pragma unroll
            for (int g = 0; g < 4; ++g) {
                int rr = (MODE == 1) ? rows_s[f * 16 + sub * 4 + g] : r0 + f * 16 + sub * 4 + g;
                A_r[f][g] = Arow[rr];
                if constexpr (MODE == 1) { s1v[f][g] = s1buf[rr]; rid[f][g] = rr; }
            }

        __syncthreads();   // X visible to all; also drains chunk0 (vmcnt0 before barrier)

        for (int t = t0; t < t1; ++t) {
            f32x4 acc[4][2];
#pragma unroll
            for (int f = 0; f < 4; ++f)
#pragma unroll
                for (int c = 0; c < 2; ++c) acc[f][c] = (f32x4){0.f, 0.f, 0.f, 0.f};

#pragma unroll
            for (int S = 0; S < 8; ++S) {
                const int ci = t * 8 + S;
                if (ci + 1 < cend) {
                    // issue next chunk (wave-private), then counted wait: the 4 newest
                    // (just-issued) stay in flight; everything older (current chunk) done.
                    const char* src = eimgw + (size_t)(ci + 1) * 32768 + lane * 16;
                    char* dst = ebase + ((ci + 1) & 1) * 32768;
#pragma unroll
                    for (int i = 0; i < 4; ++i) gload16(src + i * 1024, dst + i * 1024);
                    __builtin_amdgcn_sched_barrier(0);
                    asm volatile("s_waitcnt vmcnt(4)" ::: "memory");
                } else {
                    asm volatile("s_waitcnt vmcnt(0)" ::: "memory");
                }
                __builtin_amdgcn_sched_barrier(0);

                const char* xb = (const char*)Xs;
                const char* eb = ebase + (ci & 1) * 32768;
                short8x ah[4], al[4], ehh[2], ell[2];
#pragma unroll
                for (int f = 0; f < 4; ++f) {
                    int off = (S * 4 + sub) * 1024 + f * 256 + l15 * 16;
                    ah[f] = *(const short8x*)(xb + off);
                    al[f] = *(const short8x*)(xb + 32768 + off);
                }
#pragma unroll
                for (int c = 0; c < 2; ++c) {
                    int off = sub * 512 + c * 256 + l15 * 16;
                    ehh[c] = *(const short8x*)(eb + off);
                    ell[c] = *(const short8x*)(eb + 2048 + off);
                }
#pragma unroll
                for (int f = 0; f < 4; ++f)
#pragma unroll
                    for (int c = 0; c < 2; ++c) {
                        f32x4 a = acc[f][c];
                        a = __builtin_amdgcn_mfma_f32_16x16x32_bf16(al[f], ehh[c], a, 0, 0, 0);
                        a = __builtin_amdgcn_mfma_f32_16x16x32_bf16(ah[f], ell[c], a, 0, 0, 0);
                        a = __builtin_amdgcn_mfma_f32_16x16x32_bf16(ah[f], ehh[c], a, 0, 0, 0);
                        acc[f][c] = a;
                    }
            }

            const int cbase = t * 256 + wv * 32 + l15;   // + c*16
            if constexpr (MODE == 0) {
#pragma unroll
                for (int f = 0; f < 4; ++f)
#pragma unroll
                    for (int g = 0; g < 4; ++g) {
                        float v0 = fmaf(-2.0f, acc[f][0][g], A_r[f][g]);
                        float v1 = fmaf(-2.0f, acc[f][1][g], A_r[f][g]);
                        float tt1 = fminf(v0, v1), tt2 = fmaxf(v0, v1);
                        int tc1 = (v1 < v0) ? cbase + 16 : cbase;
                        bool upd = (tt1 < r1v[f][g]);
                        r2v[f][g] = upd ? fminf(r1v[f][g], tt2) : fminf(r2v[f][g], tt1);
                        c1v[f][g] = upd ? tc1 : c1v[f][g];
                        r1v[f][g] = upd ? tt1 : r1v[f][g];
                    }
            } else {
#pragma unroll
                for (int f = 0; f < 4; ++f)
#pragma unroll
                    for (int g = 0; g < 4; ++g) {
                        float thr = s1v[f][g] + FLAG_GAP;
#pragma unroll
                        for (int c = 0; c < 2; ++c) {
                            float v = fmaf(-2.0f, acc[f][c][g], A_r[f][g]);
                            if (v <= thr) {
                                int slot = atomicAdd(candcnt, 1);
                                if (slot < CAND_CAP)
                                    cand[slot] = ((unsigned)rid[f][g] << 13) |
                                                 (unsigned)(cbase + c * 16);
                            }
                        }
                    }
            }
        }

        if constexpr (MODE == 0) break;
        else task += gridDim.x;
    }

    if constexpr (MODE == 0) {
        __syncthreads();   // all waves done reading Xs before aliasing it as red[]
        u64* red = (u64*)Xs;   // [8 waves][64 rows][2]
#pragma unroll
        for (int f = 0; f < 4; ++f)
#pragma unroll
            for (int g = 0; g < 4; ++g) {
                u64 k1 = ((u64)fkey(r1v[f][g]) << 32) | (unsigned)c1v[f][g];
                u64 k2 = ((u64)fkey(r2v[f][g]) << 32);
#pragma unroll
                for (int m = 1; m < 16; m <<= 1) {
                    u64 o1 = __shfl_xor(k1, m, 64);
                    u64 o2 = __shfl_xor(k2, m, 64);
                    u64 mx = umax64(k1, o1);
                    k1 = umin64(k1, o1);
                    k2 = umin64(umin64(k2, o2), mx);
                }
                if (l15 == 0) {
                    int row64 = f * 16 + sub * 4 + g;
                    red[(wv * 64 + row64) * 2 + 0] = k1;
                    red[(wv * 64 + row64) * 2 + 1] = k2;
                }
            }
        __syncthreads();
        if (tid < 64) {
            u64 K1 = red[tid * 2 + 0], K2 = red[tid * 2 + 1];
#pragma unroll
            for (int w = 1; w < 8; ++w) {
                u64 o1 = red[(w * 64 + tid) * 2 + 0], o2 = red[(w * 64 + tid) * 2 + 1];
                u64 mx = umax64(K1, o1);
                K1 = umin64(K1, o1);
                K2 = umin64(umin64(K2, o2), mx);
            }
            int r = blockIdx.x * 64 + tid;
            ws_idx[r] = (int)(unsigned)(K1 & 0xffffffffull);
            float s1 = fkeyinv((unsigned)(K1 >> 32));
            float s2 = fkeyinv((unsigned)(K2 >> 32));
            s1buf[r] = s1;
            if (s2 - s1 < FLAG_GAP) {
                keybuf[r] = ~0ull;
                int slot = atomicAdd(flagcnt, 1);
                flaglist[slot] = r;
            }
        }
    }
}

// ------- Kernel C: fp64 np-semantics scoring of candidates, atomicMin merge -------
__global__ void vq_refine_cand(const float* __restrict__ X, const float* __restrict__ E,
                               const float* __restrict__ Arow, u64* __restrict__ keybuf,
                               const unsigned* __restrict__ cand,
                               const int* __restrict__ candcnt) {
    int cnt2 = *candcnt;
    cnt2 = cnt2 < CAND_CAP ? cnt2 : CAND_CAP;
    const int gw = (blockIdx.x * 256 + threadIdx.x) >> 6;   // global wave id
    const int nw = gridDim.x * 4;
    const int lane = threadIdx.x & 63;
    for (int i = gw; i < cnt2; i += nw) {
        unsigned p = cand[i];
        int row = (int)(p >> 13), code = (int)(p & 8191);
        float4 xv = *(const float4*)(X + (size_t)row * DIM + lane * 4);
        float4 ev = *(const float4*)(E + (size_t)code * DIM + lane * 4);
        double s = (double)xv.x * ev.x + (double)xv.y * ev.y +
                   (double)xv.z * ev.z + (double)xv.w * ev.w;
#pragma unroll
        for (int m = 1; m < 64; m <<= 1) s += __shfl_xor(s, m, 64);
        if (lane == 0) {
            float m32 = (float)s;
            float scr = fmaf(-2.0f, m32, Arow[row]);
            u64 key = ((u64)fkey(scr) << 32) | (unsigned)code;
            atomicMin(keybuf + row, key);
        }
    }
}

// ------- Kernel C2: apply refined winners -------
__global__ void vq_apply(const u64* __restrict__ keybuf, const int* __restrict__ flaglist,
                         const int* __restrict__ flagcnt, int* __restrict__ ws_idx) {
    int s = blockIdx.x * 256 + threadIdx.x;
    if (s < *flagcnt) {
        int r = flaglist[s];
        ws_idx[r] = (int)(unsigned)(keybuf[r] & 0xffffffffull);
    }
}

// ---------------- Kernel D: gather quantized (ST-mimic), loss partials ----------------
__global__ void vq_out(const float* __restrict__ X, const float* __restrict__ E,
                       const int* __restrict__ ws_idx, float* __restrict__ out,
                       float* __restrict__ partials) {
    const int r = (blockIdx.x * 256 + threadIdx.x) >> 6;
    const int lane = threadIdx.x & 63;
    const int idx = ws_idx[r];
    float4 e = *((const float4*)(E + (size_t)idx * DIM + lane * 4));
    float4 x = *((const float4*)(X + (size_t)r * DIM + lane * 4));
    float dx = e.x - x.x, dy = e.y - x.y, dz = e.z - x.z, dw = e.w - x.w;
    float4 o;
    o.x = x.x + dx; o.y = x.y + dy; o.z = x.z + dz; o.w = x.w + dw;
    *((float4*)(out + (size_t)r * DIM + lane * 4)) = o;
    float s = dx * dx + dy * dy + dz * dz + dw * dw;
#pragma unroll
    for (int m = 1; m < 64; m <<= 1) s += __shfl_xor(s, m, 64);
    if (lane == 0) {
        partials[r] = s;
        out[OUT_IDX + r] = (float)idx;
    }
}

// ---------------- Kernel E: deterministic loss reduction ----------------
__global__ void vq_loss(const float* __restrict__ partials, float* __restrict__ out) {
    __shared__ double sred[4];
    double s = 0.0;
    for (int i = threadIdx.x; i < N_ROWS; i += 256) s += (double)partials[i];
#pragma unroll
    for (int m = 1; m < 64; m <<= 1) s += __shfl_xor(s, m, 64);
    if ((threadIdx.x & 63) == 0) sred[threadIdx.x >> 6] = s;
    __syncthreads();
    if (threadIdx.x == 0) {
        double t = sred[0] + sred[1] + sred[2] + sred[3];
        out[OUT_LOSS] = (float)(2.0 * t / (double)OUT_Q);
    }
}

extern "C" void kernel_launch(void* const* d_in, const int* in_sizes, int n_in,
                              void* d_out, int out_size, void* d_ws, size_t ws_size,
                              hipStream_t stream) {
    const float* X = (const float*)d_in[0];
    const float* E = (const float*)d_in[1];
    float* out = (float*)d_out;
    char* ws = (char*)d_ws;

    float* Arow = (float*)(ws + WS_AROW);
    int* idx = (int*)(ws + WS_IDX);
    int* list = (int*)(ws + WS_LIST);
    int* cnt = (int*)(ws + WS_CNT);
    int* ccnt = (int*)(ws + WS_CCNT);
    float* s1buf = (float*)(ws + WS_S1);
    u64* keys = (u64*)(ws + WS_KEYS);
    float* part = (float*)(ws + WS_PART);   // aliased onto keys (dead by then)
    char* eimg = (ws_size >= (size_t)(WS_EIMG + 8 * 1024 * 1024)) ? (ws + WS_EIMG) : (char*)d_out;
    unsigned* cand = (unsigned*)((char*)d_out + (16 << 20));   // overwritten by vq_out later

    hipMemsetAsync(ws + WS_CNT, 0, 32, stream);   // zero flagcnt + candcnt
    vq_prepE<<<1024, 256, 0, stream>>>(E, eimg);
    vq_rowA<<<N_ROWS / 4, 256, 0, stream>>>(X, Arow);
    vq_scan<0><<<N_ROWS / 64, 512, 0, stream>>>(X, eimg, Arow, idx, list, cnt, keys, s1buf,
                                                cand, ccnt);
    vq_scan<1><<<512, 512, 0, stream>>>(X, eimg, Arow, idx, list, cnt, keys, s1buf, cand, ccnt);
    vq_refine_cand<<<1024, 256, 0, stream>>>(X, E, Arow, keys, cand, ccnt);
    vq_apply<<<128, 256, 0, stream>>>(keys, list, cnt, idx);
    vq_out<<<N_ROWS / 4, 256, 0, stream>>>(X, E, idx, out, part);
    vq_loss<<<1, 256, 0, stream>>>(part, out);
}